// Round 2
// baseline (142.572 us; speedup 1.0000x reference)
//
#include <hip/hip_runtime.h>
#include <math.h>

#define NB    32
#define NPTS  131072
#define NS    6
#define HH    256
#define WW    256
#define IMG   (HH * WW)          // 65536
#define RB    16                 // y-band regions per batch (16 rows each)
#define NCH2  32                 // sub-buckets per band = blocks per batch
#define SCAP2 224                // records per (block,band) sub-bucket (mean ~140 center band, +7 sigma)
#define KEYB  (NCH2 * SCAP2 * 2) // 14336 B of u16 keys per region
#define ZB    (NCH2 * SCAP2 * 4) // 28672 B of f32 z per region
#define REG3  (KEYB + ZB)        // 43008 B per (b,band) region (256-aligned)

// ---- ws layout (bytes) ----
// cnts @ 0     : NB*RB*NCH2 u32 = 65536   (per (b,band,block) record counts, plain stores)
// pmm  @ 65536 : NB*32 float2   = 8192    (per-block z min/max partials)
// pmin @ 73728 : NB*RB*NS u32   = 12288   (per (b,band,s) count min, agent-scope atomics)
// pmax @ 86016 : NB*RB*NS u32   = 12288
// flag @ 98304 : NB u32         = 128     (per-batch arrival counters)
// bkt  @ 98560 : NB*RB regions x 43008 B  = 22,020,096
#define WS_CNT     0
#define WS_PMM     (65536 / 8)          // float2 index
#define WS_PMIN    (73728 / 4)
#define WS_PMAX    (86016 / 4)
#define WS_FLG4    (98304 / 4)          // u32 index
#define WS_BKT     98560
#define WS_NEEDED  ((size_t)WS_BKT + (size_t)NB * RB * REG3)   // 22,118,656

// ---- monotone float<->uint encoding (fallback path only) ----
__device__ __forceinline__ unsigned int f2o(float f) {
    unsigned int u = __float_as_uint(f);
    return (u & 0x80000000u) ? ~u : (u | 0x80000000u);
}
__device__ __forceinline__ float o2f(unsigned int u) {
    return __uint_as_float((u & 0x80000000u) ? (u ^ 0x80000000u) : ~u);
}

// np.linspace(0,1,7).astype(f32) interior values as exact hexfloats
#define A16 0x1.555556p-3f
#define A26 0x1.555556p-2f
#define A36 0.5f
#define A46 0x1.555556p-1f
#define A56 0x1.AAAAAAp-1f
// loose prefilter: approx scale 255/2.000001 (error vs exact path < 6e-5)
#define C1A 127.49994f

__device__ __forceinline__ void compute_edges(float zmin, float zmax,
                                              float& e1, float& e2, float& e3,
                                              float& e4, float& e5, float& e6) {
    float range = __fsub_rn(zmax, zmin);
    e1 = __fadd_rn(zmin, __fmul_rn(range, A16));
    e2 = __fadd_rn(zmin, __fmul_rn(range, A26));
    e3 = __fadd_rn(zmin, __fmul_rn(range, A36));
    e4 = __fadd_rn(zmin, __fmul_rn(range, A46));
    e5 = __fadd_rn(zmin, __fmul_rn(range, A56));
    e6 = __fadd_rn(zmin, range);
}

// ======================= fast path (2 kernels: k_p1 + fused k_p23) =======================

// k_p1: read xyz once; stage valid records per band in LDS (u16 key + f32 z split);
// flush coalesced into statically-owned sub-bucket slots; plain-store counts + z minmax.
// (unchanged from the verified 121.7 us version, + per-batch flag zeroing)
__global__ __launch_bounds__(1024) void k_p1(const float* __restrict__ xyz,
                                             unsigned int* __restrict__ ws,
                                             char* __restrict__ bkt) {
    const int b  = blockIdx.y;
    const int cx = blockIdx.x;                 // 0..31 chunk within batch
    const int t  = threadIdx.x;                // 1024 threads, 4 points each
    const int wave = t >> 6;
    __shared__ unsigned int cnt[RB];
    __shared__ unsigned short stage_k[RB][SCAP2];   // 7168 B
    __shared__ float stage_z[RB][SCAP2];            // 14336 B
    __shared__ float smin[16], smax[16];
    if (t < RB) cnt[t] = 0u;
    if (cx == 0 && t == 0)
        __hip_atomic_store(&ws[WS_FLG4 + b], 0u, __ATOMIC_RELAXED,
                           __HIP_MEMORY_SCOPE_AGENT);
    __syncthreads();

    const int g = cx * 1024 + t;
    const float4* p4 = (const float4*)(xyz + (size_t)b * NPTS * 3);
    float4 v0 = p4[3 * g + 0];
    float4 v1 = p4[3 * g + 1];
    float4 v2 = p4[3 * g + 2];
    float xs[4] = {v0.x, v0.w, v1.z, v2.y};
    float ys[4] = {v0.y, v1.x, v1.w, v2.z};
    float zs[4] = {v0.z, v1.y, v2.x, v2.w};

    #pragma unroll
    for (int p = 0; p < 4; ++p) {
        float ty = __fadd_rn(ys[p], 1.0f);
        float tx = __fadd_rn(xs[p], 1.0f);
        // loose prefilter (over-accepting); exact path only for plausible pts
        float gya = ty * C1A, gxa = tx * C1A;
        if (gya > -0.02f && gya < 256.02f && gxa > -0.02f && gxa < 256.02f) {
            // bit-exact reference coord math (all f32-rounded steps, no FMA)
            float gy = __fmul_rn(__fdiv_rn(ty, 2.000001f), 255.0f);
            float gx = __fmul_rn(__fdiv_rn(tx, 2.000001f), 255.0f);
            if (gy >= 0.0f && gy < 256.0f && gx >= 0.0f && gx < 256.0f) {
                int iy = (int)gy, ix = (int)gx;
                int r = iy >> 4;
                unsigned int off = atomicAdd(&cnt[r], 1u);
                if (off < SCAP2) {
                    stage_k[r][off] = (unsigned short)((iy << 8) | ix);
                    stage_z[r][off] = zs[p];
                }
            }
        }
    }

    // fused z min/max over ALL points (reference reduces over all N)
    float lmin = fminf(fminf(zs[0], zs[1]), fminf(zs[2], zs[3]));
    float lmax = fmaxf(fmaxf(zs[0], zs[1]), fmaxf(zs[2], zs[3]));
    #pragma unroll
    for (int o = 32; o >= 1; o >>= 1) {
        lmin = fminf(lmin, __shfl_down(lmin, o));
        lmax = fmaxf(lmax, __shfl_down(lmax, o));
    }
    if ((t & 63) == 0) { smin[wave] = lmin; smax[wave] = lmax; }
    __syncthreads();   // cnt + stage + smin/smax final

    if (t == 0) {
        float m = smin[0], M = smax[0];
        #pragma unroll
        for (int w = 1; w < 16; ++w) { m = fminf(m, smin[w]); M = fmaxf(M, smax[w]); }
        ((float2*)ws)[WS_PMM + b * 32 + cx] = make_float2(m, M);   // plain store
    }
    if (t < RB)
        ws[WS_CNT + (b * RB + t) * NCH2 + cx] = min(cnt[t], (unsigned)SCAP2);

    // coalesced flush: this block statically owns slot range [cx*SCAP2, +SCAP2)
    for (int r = 0; r < RB; ++r) {
        unsigned int n = min(cnt[r], (unsigned)SCAP2);
        char* region = bkt + (size_t)(b * RB + r) * REG3;
        // keys flushed as paired u32 (one trailing garbage u16 beyond n is never read)
        unsigned int* kdst = (unsigned int*)(region + (size_t)cx * SCAP2 * 2);
        const unsigned int* ksrc = (const unsigned int*)&stage_k[r][0];
        unsigned int nk = (n + 1) >> 1;
        for (unsigned int i = t; i < nk; i += 1024) kdst[i] = ksrc[i];
        float* zdst = (float*)(region + KEYB) + (size_t)cx * SCAP2;
        for (unsigned int i = t; i < n; i += 1024) zdst[i] = stage_z[r][i];
    }
}

// k_p23: fusion of old k_p2 + k_norm via per-batch arrival counters (NO cooperative
// launch -- plain hipLaunchKernelGGL, graph-capture safe).
// Phase 2: per (b,band) LDS u16 histogram from records (coalesced via prefix-sum +
//          binary search); per-slice count min/max partials -> ws (agent atomics).
// arrive(flag[b]); spin until flag[b]==16  (all 512 blocks co-resident: 54.7 KB LDS
//          -> 2 blocks/CU x 256 CU = 512 = grid, so the spin cannot deadlock)
// Phase 3: reduce 16 band partials -> (b,s) min/max, build 6 LUTs in LDS,
//          normalize OWN band directly from the LDS hist (no u8 pack round-trip).
__global__ __launch_bounds__(512, 4) void k_p23(char* __restrict__ bkt,
                                                unsigned int* __restrict__ ws,
                                                float* __restrict__ out) {
    const int r = blockIdx.x;        // 0..15 (y band)
    const int b = blockIdx.y;
    const int t = threadIdx.x;       // 512 threads
    const int wave = t >> 6;
    __shared__ unsigned int hist[NS * 16 * WW / 2];  // 12288 u32 = 24576 u16 counts (48 KB)
    __shared__ unsigned int cct[NCH2];
    __shared__ unsigned int psum[NCH2 + 1];
    __shared__ unsigned int rmin[8][NS], rmax[8][NS];
    __shared__ float lut[NS][256];                   // 6 KB
    __shared__ float bcmn[NS], bcdn[NS];

    // reduce per-block z partials (uniform scalar loads) — identical op order to old k_p2
    const float2* pmm = (const float2*)ws + WS_PMM + b * 32;
    float zmin = INFINITY, zmax = -INFINITY;
    for (int i = 0; i < 32; ++i) {
        float2 v = pmm[i];
        zmin = fminf(zmin, v.x); zmax = fmaxf(zmax, v.y);
    }
    float e1, e2, e3, e4, e5, e6;
    compute_edges(zmin, zmax, e1, e2, e3, e4, e5, e6);

    for (int i = t; i < NS * 16 * WW / 2; i += 512) hist[i] = 0u;
    if (t < NCH2) cct[t] = ws[WS_CNT + (b * RB + r) * NCH2 + t];
    __syncthreads();
    if (t == 0) {
        unsigned int s0 = 0; psum[0] = 0;
        for (int c = 0; c < NCH2; ++c) { s0 += cct[c]; psum[c + 1] = s0; }
    }
    __syncthreads();

    const unsigned int T = psum[NCH2];
    char* region = bkt + (size_t)(b * RB + r) * REG3;
    const unsigned short* keys = (const unsigned short*)region;
    const float* zarr = (const float*)(region + KEYB);
    for (unsigned int i = t; i < T; i += 512) {
        int lo = 0, hi = NCH2;               // psum[lo] <= i < psum[lo+1]
        #pragma unroll
        for (int st = 0; st < 5; ++st) { int mid = (lo + hi) >> 1; if (psum[mid] <= i) lo = mid; else hi = mid; }
        unsigned int j = lo * SCAP2 + (i - psum[lo]);
        unsigned int key = keys[j];
        float z = zarr[j];
        if (z >= zmin && z < e6) {
            int s = (int)(z >= e1) + (int)(z >= e2) + (int)(z >= e3) +
                    (int)(z >= e4) + (int)(z >= e5);
            int bin = (s << 12) | ((int)key & 0x0F00) | ((int)key & 0xFF);
            atomicAdd(&hist[bin >> 1], 1u << ((bin & 1) * 16));
        }
    }
    __syncthreads();

    // per-slice count min/max partials over this band's hist (u16 values)
    #pragma unroll
    for (int s = 0; s < NS; ++s) {
        unsigned int a = 0xFFFFFFFFu, m = 0u;
        #pragma unroll
        for (int j = 0; j < 4; ++j) {
            unsigned int u = hist[(s << 11) + (j << 9) + t];   // 2048 u32 per slice
            unsigned int c0 = u & 0xFFFFu, c1 = u >> 16;
            a = min(a, min(c0, c1));
            m = max(m, max(c0, c1));
        }
        #pragma unroll
        for (int o = 32; o >= 1; o >>= 1) {
            a = min(a, (unsigned)__shfl_down((int)a, o));
            m = max(m, (unsigned)__shfl_down((int)m, o));
        }
        if ((t & 63) == 0) { rmin[wave][s] = a; rmax[wave][s] = m; }
    }
    __syncthreads();
    if (t < NS) {
        unsigned int a = rmin[0][t], m = rmax[0][t];
        #pragma unroll
        for (int w = 1; w < 8; ++w) { a = min(a, rmin[w][t]); m = max(m, rmax[w][t]); }
        __hip_atomic_store(&ws[WS_PMIN + (b * RB + r) * NS + t], a,
                           __ATOMIC_RELAXED, __HIP_MEMORY_SCOPE_AGENT);
        __hip_atomic_store(&ws[WS_PMAX + (b * RB + r) * NS + t], m,
                           __ATOMIC_RELAXED, __HIP_MEMORY_SCOPE_AGENT);
    }

    // ---- per-batch arrival barrier (hist stays live in LDS!) ----
    __syncthreads();                 // drains vmcnt: partial stores at coherent point
    if (t == 0) {
        __threadfence();
        atomicAdd(&ws[WS_FLG4 + b], 1u);      // arrive (device-scope)
        while (__hip_atomic_load(&ws[WS_FLG4 + b], __ATOMIC_RELAXED,
                                 __HIP_MEMORY_SCOPE_AGENT) < (unsigned)RB)
            __builtin_amdgcn_s_sleep(2);
    }
    __syncthreads();

    // (b,s) global min/max over 16 bands -> LUT coefficients
    if (t < NS) {
        unsigned int a = 0xFFFFFFFFu, m = 0u;
        for (int rr = 0; rr < RB; ++rr) {
            a = min(a, __hip_atomic_load(&ws[WS_PMIN + (b * RB + rr) * NS + t],
                                         __ATOMIC_RELAXED, __HIP_MEMORY_SCOPE_AGENT));
            m = max(m, __hip_atomic_load(&ws[WS_PMAX + (b * RB + rr) * NS + t],
                                         __ATOMIC_RELAXED, __HIP_MEMORY_SCOPE_AGENT));
        }
        float mn = log1pf((float)a);
        bcmn[t] = mn;
        bcdn[t] = __fadd_rn(__fsub_rn(log1pf((float)m), mn), 1e-6f);
    }
    __syncthreads();
    for (int i = t; i < NS * 256; i += 512) {
        int s = i >> 8, v = i & 255;
        lut[s][v] = __fdiv_rn(__fsub_rn(log1pf((float)v), bcmn[s]), bcdn[s]);
    }
    __syncthreads();

    // normalize OWN band straight from LDS hist: 6 slices x 16 rows x 64 float4
    float4* o4 = (float4*)out;
    #pragma unroll
    for (int k = 0; k < 12; ++k) {
        int f4  = k * 512 + t;           // 0..6143
        int s   = f4 >> 10;              // 1024 float4 per slice (16 rows x 64)
        int rem = f4 & 1023;
        int yl  = rem >> 6, xq = rem & 63;
        int bin0 = (s << 12) | (yl << 8) | (xq << 2);   // even -> aligned u32 pair
        unsigned int u  = hist[(bin0 >> 1)];
        unsigned int v2 = hist[(bin0 >> 1) + 1];
        float4 o;
        o.x = lut[s][min(u & 0xFFFFu, 255u)];
        o.y = lut[s][min(u >> 16, 255u)];
        o.z = lut[s][min(v2 & 0xFFFFu, 255u)];
        o.w = lut[s][min(v2 >> 16, 255u)];
        o4[(size_t)(b * NS + s) * (IMG / 4) + ((r << 4) + yl) * 64 + xq] = o;
    }
}

// ======================= R1 minimal fallback (ws too small) =======================

__global__ void k_init_o(unsigned int* __restrict__ mm) {
    int t = threadIdx.x;
    if (t < NB) { mm[2 * t] = 0xFFFFFFFFu; mm[2 * t + 1] = 0u; }
}

__global__ __launch_bounds__(256) void k_minmax_o(const float* __restrict__ xyz,
                                                  unsigned int* __restrict__ mm) {
    const int b = blockIdx.y;
    const float4* p4 = (const float4*)(xyz + (size_t)b * NPTS * 3);
    const int nthreads = gridDim.x * blockDim.x;
    const int t = blockIdx.x * blockDim.x + threadIdx.x;
    float lmin = INFINITY, lmax = -INFINITY;
    for (int g = t; g < NPTS / 4; g += nthreads) {
        float4 v0 = p4[3 * g + 0];
        float4 v1 = p4[3 * g + 1];
        float4 v2 = p4[3 * g + 2];
        lmin = fminf(fminf(fminf(lmin, v0.z), v1.y), fminf(v2.x, v2.w));
        lmax = fmaxf(fmaxf(fmaxf(lmax, v0.z), v1.y), fmaxf(v2.x, v2.w));
    }
    #pragma unroll
    for (int o = 32; o >= 1; o >>= 1) {
        lmin = fminf(lmin, __shfl_down(lmin, o));
        lmax = fmaxf(lmax, __shfl_down(lmax, o));
    }
    __shared__ float smin[4], smax[4];
    int wave = threadIdx.x >> 6, lane = threadIdx.x & 63;
    if (lane == 0) { smin[wave] = lmin; smax[wave] = lmax; }
    __syncthreads();
    if (threadIdx.x == 0) {
        float m = smin[0], M = smax[0];
        #pragma unroll
        for (int w = 1; w < 4; ++w) { m = fminf(m, smin[w]); M = fmaxf(M, smax[w]); }
        atomicMin(&mm[2 * b], f2o(m));
        atomicMax(&mm[2 * b + 1], f2o(M));
    }
}

__device__ __forceinline__ void hist_point_o(float x, float y, float z, int b,
                                             float zmin, float e1, float e2, float e3,
                                             float e4, float e5, float e6,
                                             float* __restrict__ out) {
    float gx = __fmul_rn(__fdiv_rn(__fadd_rn(x, 1.0f), 2.000001f), 255.0f);
    float gy = __fmul_rn(__fdiv_rn(__fadd_rn(y, 1.0f), 2.000001f), 255.0f);
    bool valid = (gy >= 0.0f) && (gy < 256.0f) && (gx >= 0.0f) && (gx < 256.0f);
    if (valid && z >= zmin && z < e6) {
        int s = (int)(z >= e1) + (int)(z >= e2) + (int)(z >= e3) +
                (int)(z >= e4) + (int)(z >= e5);
        atomicAdd(out + ((size_t)(b * NS + s) * IMG + ((int)gy) * WW + (int)gx), 1.0f);
    }
}

__global__ __launch_bounds__(256) void k_hist_o(const float* __restrict__ xyz,
                                                const unsigned int* __restrict__ mm,
                                                float* __restrict__ out) {
    const int b = blockIdx.y;
    const int t = blockIdx.x * blockDim.x + threadIdx.x;
    const float zmin = o2f(mm[2 * b]);
    const float zmax = o2f(mm[2 * b + 1]);
    float e1, e2, e3, e4, e5, e6;
    compute_edges(zmin, zmax, e1, e2, e3, e4, e5, e6);
    const float4* p4 = (const float4*)(xyz + (size_t)b * NPTS * 3);
    float4 v0 = p4[3 * t + 0];
    float4 v1 = p4[3 * t + 1];
    float4 v2 = p4[3 * t + 2];
    hist_point_o(v0.x, v0.y, v0.z, b, zmin, e1, e2, e3, e4, e5, e6, out);
    hist_point_o(v0.w, v1.x, v1.y, b, zmin, e1, e2, e3, e4, e5, e6, out);
    hist_point_o(v1.z, v1.w, v2.x, b, zmin, e1, e2, e3, e4, e5, e6, out);
    hist_point_o(v2.y, v2.z, v2.w, b, zmin, e1, e2, e3, e4, e5, e6, out);
}

__global__ __launch_bounds__(1024) void k_norm_o(float* __restrict__ out) {
    float4* img4 = (float4*)(out + (size_t)blockIdx.x * IMG);
    const int t = threadIdx.x;
    float lmin = INFINITY, lmax = -INFINITY;
    for (int i = t; i < IMG / 4; i += 1024) {
        float4 v = img4[i];
        lmin = fminf(lmin, fminf(fminf(v.x, v.y), fminf(v.z, v.w)));
        lmax = fmaxf(lmax, fmaxf(fmaxf(v.x, v.y), fmaxf(v.z, v.w)));
    }
    #pragma unroll
    for (int o = 32; o >= 1; o >>= 1) {
        lmin = fminf(lmin, __shfl_down(lmin, o));
        lmax = fmaxf(lmax, __shfl_down(lmax, o));
    }
    __shared__ float smin[16], smax[16], bc[2];
    int wave = t >> 6, lane = t & 63;
    if (lane == 0) { smin[wave] = lmin; smax[wave] = lmax; }
    __syncthreads();
    if (t == 0) {
        float m = smin[0], M = smax[0];
        #pragma unroll
        for (int w = 1; w < 16; ++w) { m = fminf(m, smin[w]); M = fmaxf(M, smax[w]); }
        bc[0] = m; bc[1] = M;
    }
    __syncthreads();
    const float mn = log1pf(bc[0]);
    const float mx = log1pf(bc[1]);
    const float denom = __fadd_rn(__fsub_rn(mx, mn), 1e-6f);
    for (int i = t; i < IMG / 4; i += 1024) {
        float4 v = img4[i];
        v.x = __fdiv_rn(__fsub_rn(log1pf(v.x), mn), denom);
        v.y = __fdiv_rn(__fsub_rn(log1pf(v.y), mn), denom);
        v.z = __fdiv_rn(__fsub_rn(log1pf(v.z), mn), denom);
        v.w = __fdiv_rn(__fsub_rn(log1pf(v.w), mn), denom);
        img4[i] = v;
    }
}

extern "C" void kernel_launch(void* const* d_in, const int* in_sizes, int n_in,
                              void* d_out, int out_size, void* d_ws, size_t ws_size,
                              hipStream_t stream) {
    const float* xyz = (const float*)d_in[0];
    float* out = (float*)d_out;
    unsigned int* ws = (unsigned int*)d_ws;

    if (ws_size >= WS_NEEDED) {
        char* bkt = (char*)d_ws + WS_BKT;
        hipLaunchKernelGGL(k_p1, dim3(NCH2, NB), dim3(1024), 0, stream, xyz, ws, bkt);
        hipLaunchKernelGGL(k_p23, dim3(RB, NB), dim3(512), 0, stream, bkt, ws, out);
    } else {
        hipMemsetAsync(d_out, 0, (size_t)out_size * sizeof(float), stream);
        hipLaunchKernelGGL(k_init_o, dim3(1), dim3(64), 0, stream, ws);
        hipLaunchKernelGGL(k_minmax_o, dim3(32, NB), dim3(256), 0, stream, xyz, ws);
        hipLaunchKernelGGL(k_hist_o, dim3(NPTS / 1024, NB), dim3(256), 0, stream, xyz, ws, out);
        hipLaunchKernelGGL(k_norm_o, dim3(NB * NS), dim3(1024), 0, stream, out);
    }
}

// Round 3
// 126.494 us; speedup vs baseline: 1.1271x; 1.1271x over previous
//
#include <hip/hip_runtime.h>
#include <math.h>

#define NB    32
#define NPTS  131072
#define NS    6
#define HH    256
#define WW    256
#define IMG   (HH * WW)          // 65536
#define RB    16                 // y-band regions per batch (16 rows each)
#define NCH2  32                 // sub-buckets per band = blocks per batch
#define SCAP2 224                // records per (block,band) sub-bucket (mean ~140 center band, +7 sigma)
#define KEYB  (NCH2 * SCAP2 * 2) // 14336 B of u16 keys per region
#define ZB    (NCH2 * SCAP2 * 4) // 28672 B of f32 z per region
#define REG3  (KEYB + ZB)        // 43008 B per (b,band) region (256-aligned)
// phase2 reuses first 24576 B of each region as u8 hist [s][row16][col]

// ---- ws layout (bytes) ----
// cnts @ 0     : NB*RB*NCH2 u32 = 65536   (per (b,band,block) record counts, plain stores)
// pmm  @ 65536 : NB*32 float2   = 8192    (per-block z min/max partials)
// pmin @ 73728 : NB*RB*NS u32   = 12288   (per (b,band,s) count min)
// pmax @ 86016 : NB*RB*NS u32   = 12288
// bkt  @ 98304 : NB*RB regions x 43008 B  = 22,020,096
#define WS_CNT     0
#define WS_PMM     (65536 / 8)          // float2 index
#define WS_PMIN    (73728 / 4)
#define WS_PMAX    (86016 / 4)
#define WS_BKT     98304
#define WS_NEEDED  ((size_t)WS_BKT + (size_t)NB * RB * REG3)   // 22,118,400

// ---- monotone float<->uint encoding (fallback path only) ----
__device__ __forceinline__ unsigned int f2o(float f) {
    unsigned int u = __float_as_uint(f);
    return (u & 0x80000000u) ? ~u : (u | 0x80000000u);
}
__device__ __forceinline__ float o2f(unsigned int u) {
    return __uint_as_float((u & 0x80000000u) ? (u ^ 0x80000000u) : ~u);
}

// np.linspace(0,1,7).astype(f32) interior values as exact hexfloats
#define A16 0x1.555556p-3f
#define A26 0x1.555556p-2f
#define A36 0.5f
#define A46 0x1.555556p-1f
#define A56 0x1.AAAAAAp-1f
// loose prefilter: approx scale 255/2.000001 (error vs exact path < 6e-5)
#define C1A 127.49994f

__device__ __forceinline__ void compute_edges(float zmin, float zmax,
                                              float& e1, float& e2, float& e3,
                                              float& e4, float& e5, float& e6) {
    float range = __fsub_rn(zmax, zmin);
    e1 = __fadd_rn(zmin, __fmul_rn(range, A16));
    e2 = __fadd_rn(zmin, __fmul_rn(range, A26));
    e3 = __fadd_rn(zmin, __fmul_rn(range, A36));
    e4 = __fadd_rn(zmin, __fmul_rn(range, A46));
    e5 = __fadd_rn(zmin, __fmul_rn(range, A56));
    e6 = __fadd_rn(zmin, range);
}

// ======================= fast path (3 kernels, no global atomics) =======================

// k_p1: read xyz once; stage valid records per band in LDS (u16 key + f32 z split);
// flush coalesced into statically-owned sub-bucket slots; plain-store counts + z minmax.
// (byte-identical to the verified 121.7 us version)
__global__ __launch_bounds__(1024) void k_p1(const float* __restrict__ xyz,
                                             unsigned int* __restrict__ ws,
                                             char* __restrict__ bkt) {
    const int b  = blockIdx.y;
    const int cx = blockIdx.x;                 // 0..31 chunk within batch
    const int t  = threadIdx.x;                // 1024 threads, 4 points each
    const int wave = t >> 6;
    __shared__ unsigned int cnt[RB];
    __shared__ unsigned short stage_k[RB][SCAP2];   // 7168 B
    __shared__ float stage_z[RB][SCAP2];            // 14336 B
    __shared__ float smin[16], smax[16];
    if (t < RB) cnt[t] = 0u;
    __syncthreads();

    const int g = cx * 1024 + t;
    const float4* p4 = (const float4*)(xyz + (size_t)b * NPTS * 3);
    float4 v0 = p4[3 * g + 0];
    float4 v1 = p4[3 * g + 1];
    float4 v2 = p4[3 * g + 2];
    float xs[4] = {v0.x, v0.w, v1.z, v2.y};
    float ys[4] = {v0.y, v1.x, v1.w, v2.z};
    float zs[4] = {v0.z, v1.y, v2.x, v2.w};

    #pragma unroll
    for (int p = 0; p < 4; ++p) {
        float ty = __fadd_rn(ys[p], 1.0f);
        float tx = __fadd_rn(xs[p], 1.0f);
        // loose prefilter (over-accepting); exact path only for plausible pts
        float gya = ty * C1A, gxa = tx * C1A;
        if (gya > -0.02f && gya < 256.02f && gxa > -0.02f && gxa < 256.02f) {
            // bit-exact reference coord math (all f32-rounded steps, no FMA)
            float gy = __fmul_rn(__fdiv_rn(ty, 2.000001f), 255.0f);
            float gx = __fmul_rn(__fdiv_rn(tx, 2.000001f), 255.0f);
            if (gy >= 0.0f && gy < 256.0f && gx >= 0.0f && gx < 256.0f) {
                int iy = (int)gy, ix = (int)gx;
                int r = iy >> 4;
                unsigned int off = atomicAdd(&cnt[r], 1u);
                if (off < SCAP2) {
                    stage_k[r][off] = (unsigned short)((iy << 8) | ix);
                    stage_z[r][off] = zs[p];
                }
            }
        }
    }

    // fused z min/max over ALL points (reference reduces over all N)
    float lmin = fminf(fminf(zs[0], zs[1]), fminf(zs[2], zs[3]));
    float lmax = fmaxf(fmaxf(zs[0], zs[1]), fmaxf(zs[2], zs[3]));
    #pragma unroll
    for (int o = 32; o >= 1; o >>= 1) {
        lmin = fminf(lmin, __shfl_down(lmin, o));
        lmax = fmaxf(lmax, __shfl_down(lmax, o));
    }
    if ((t & 63) == 0) { smin[wave] = lmin; smax[wave] = lmax; }
    __syncthreads();   // cnt + stage + smin/smax final

    if (t == 0) {
        float m = smin[0], M = smax[0];
        #pragma unroll
        for (int w = 1; w < 16; ++w) { m = fminf(m, smin[w]); M = fmaxf(M, smax[w]); }
        ((float2*)ws)[WS_PMM + b * 32 + cx] = make_float2(m, M);   // plain store
    }
    if (t < RB)
        ws[WS_CNT + (b * RB + t) * NCH2 + cx] = min(cnt[t], (unsigned)SCAP2);

    // coalesced flush: this block statically owns slot range [cx*SCAP2, +SCAP2)
    for (int r = 0; r < RB; ++r) {
        unsigned int n = min(cnt[r], (unsigned)SCAP2);
        char* region = bkt + (size_t)(b * RB + r) * REG3;
        // keys flushed as paired u32 (one trailing garbage u16 beyond n is never read)
        unsigned int* kdst = (unsigned int*)(region + (size_t)cx * SCAP2 * 2);
        const unsigned int* ksrc = (const unsigned int*)&stage_k[r][0];
        unsigned int nk = (n + 1) >> 1;
        for (unsigned int i = t; i < nk; i += 1024) kdst[i] = ksrc[i];
        float* zdst = (float*)(region + KEYB) + (size_t)cx * SCAP2;
        for (unsigned int i = t; i < n; i += 1024) zdst[i] = stage_z[r][i];
    }
}

// k_p2: per (b,band) LDS u16 histogram from records.
// ROUND-2 CHANGE (driven by k_p23 counters: VALUBusy 12%, occ 37%, latency-bound):
//  - binary-search record indexing REPLACED by static sub-bucket ownership
//    (thread t -> bucket t>>5, lane t&31 strides by 32): removes the 5 serially-
//    dependent LDS reads per record that dominated the dependence chain.
//  - 1024 threads/block (was 512): 2 blocks/CU by thread limit -> 32 waves/CU.
// Histogram contents identical (same record set, adds commute) => bit-identical output.
__global__ __launch_bounds__(1024) void k_p2(char* __restrict__ bkt,
                                             unsigned int* __restrict__ ws) {
    const int r = blockIdx.x;        // 0..15 (y band)
    const int b = blockIdx.y;
    const int t = threadIdx.x;       // 1024 threads
    const int wave = t >> 6;
    __shared__ unsigned int hist[NS * 16 * WW / 2];  // 12288 u32 = 24576 u16 counts
    __shared__ unsigned int cct[NCH2];
    __shared__ unsigned int rmin[16][NS], rmax[16][NS];

    // reduce per-block z partials (uniform scalar loads)
    const float2* pmm = (const float2*)ws + WS_PMM + b * 32;
    float zmin = INFINITY, zmax = -INFINITY;
    for (int i = 0; i < 32; ++i) {
        float2 v = pmm[i];
        zmin = fminf(zmin, v.x); zmax = fmaxf(zmax, v.y);
    }
    float e1, e2, e3, e4, e5, e6;
    compute_edges(zmin, zmax, e1, e2, e3, e4, e5, e6);

    for (int i = t; i < NS * 16 * WW / 2; i += 1024) hist[i] = 0u;
    if (t < NCH2) cct[t] = ws[WS_CNT + (b * RB + r) * NCH2 + t];
    __syncthreads();

    char* region = bkt + (size_t)(b * RB + r) * REG3;
    const unsigned short* keys = (const unsigned short*)region;
    const float* zarr = (const float*)(region + KEYB);

    // static ownership: 32 lanes per bucket, no prefix-sum, no binary search
    const int c = t >> 5;                    // bucket 0..31
    const int l = t & 31;
    const unsigned int n = cct[c];           // <= SCAP2 (capped by k_p1)
    const unsigned int base = (unsigned int)c * SCAP2;
    for (unsigned int i = l; i < n; i += 32) {
        unsigned int j = base + i;
        unsigned int key = keys[j];
        float z = zarr[j];
        if (z >= zmin && z < e6) {
            int s = (int)(z >= e1) + (int)(z >= e2) + (int)(z >= e3) +
                    (int)(z >= e4) + (int)(z >= e5);
            int bin = (s << 12) | ((int)key & 0x0F00) | ((int)key & 0xFF);
            atomicAdd(&hist[bin >> 1], 1u << ((bin & 1) * 16));
        }
    }
    __syncthreads();   // all record reads done -> safe to overwrite region

    // write u8-packed hist into OWN region (counts < 256: Poisson lambda ~0.6, max ~10)
    unsigned int* dst = (unsigned int*)region;   // 6144 u32 = 24576 B, [s][row16][col] u8
    #pragma unroll
    for (int s = 0; s < NS; ++s) {
        int i = (s << 10) + t;                   // u32-of-u8 index: 1024 per slice
        unsigned int u = hist[2 * i], v = hist[2 * i + 1];
        unsigned int c0 = u & 0xFFFFu, c1 = u >> 16;
        unsigned int c2 = v & 0xFFFFu, c3 = v >> 16;
        unsigned int a = min(min(c0, c1), min(c2, c3));
        unsigned int m = max(max(c0, c1), max(c2, c3));
        dst[i] = (u & 0xFFu) | ((u >> 8) & 0xFF00u) |
                 ((v & 0xFFu) << 16) | (((v >> 8) & 0xFF00u) << 16);
        #pragma unroll
        for (int o = 32; o >= 1; o >>= 1) {
            a = min(a, (unsigned)__shfl_down((int)a, o));
            m = max(m, (unsigned)__shfl_down((int)m, o));
        }
        if ((t & 63) == 0) { rmin[wave][s] = a; rmax[wave][s] = m; }
    }
    __syncthreads();
    if (t < NS) {
        unsigned int a = rmin[0][t], m = rmax[0][t];
        #pragma unroll
        for (int w = 1; w < 16; ++w) { a = min(a, rmin[w][t]); m = max(m, rmax[w][t]); }
        ws[WS_PMIN + (b * RB + r) * NS + t] = a;   // plain stores
        ws[WS_PMAX + (b * RB + r) * NS + t] = m;
    }
}

// k_norm: complete LUT normalize (u8 counts => 256-entry LUT covers every value);
// per element = u32 load (4 cells), 4 LDS lookups, float4 store. Pure streaming.
// (byte-identical to the verified 121.7 us version)
__global__ __launch_bounds__(1024) void k_norm(const char* __restrict__ bkt,
                                               const unsigned int* __restrict__ ws,
                                               float* __restrict__ out) {
    const int q = blockIdx.x;          // 768 blocks: (b*6+s)*4 + quarter
    const int img = q >> 2;            // b*NS+s
    const int quarter = q & 3;
    const int b = img / NS, s = img - b * NS;
    const int t = threadIdx.x;
    __shared__ float bc[2];
    __shared__ float lut[256];

    if (t < 64) {   // reduce 16 band partials for (b,s)
        unsigned int a = 0xFFFFFFFFu, m = 0u;
        if (t < RB) {
            a = ws[WS_PMIN + (b * RB + t) * NS + s];
            m = ws[WS_PMAX + (b * RB + t) * NS + s];
        }
        #pragma unroll
        for (int o = 8; o >= 1; o >>= 1) {
            a = min(a, (unsigned)__shfl_down((int)a, o));
            m = max(m, (unsigned)__shfl_down((int)m, o));
        }
        if (t == 0) { bc[0] = log1pf((float)a); bc[1] = log1pf((float)m); }
    }
    __syncthreads();
    const float mn = bc[0];
    const float denom = __fadd_rn(__fsub_rn(bc[1], mn), 1e-6f);
    if (t < 256)
        lut[t] = __fdiv_rn(__fsub_rn(log1pf((float)t), mn), denom);
    __syncthreads();

    float4* out4 = (float4*)out + (size_t)img * (IMG / 4) + quarter * 4096;
    #pragma unroll
    for (int j = 0; j < 4; ++j) {
        int idx4 = j * 1024 + t;                  // 4096 float4 per quarter
        int f = idx4 << 2;
        int y = (quarter << 6) + (f >> 8);
        int x = f & 255;
        const char* region = bkt + (size_t)(b * RB + (y >> 4)) * REG3;
        unsigned int u = *(const unsigned int*)(region + ((((s << 4) | (y & 15)) << 8) | x));
        float4 v;
        v.x = lut[u & 0xFFu];
        v.y = lut[(u >> 8) & 0xFFu];
        v.z = lut[(u >> 16) & 0xFFu];
        v.w = lut[u >> 24];
        out4[idx4] = v;
    }
}

// ======================= R1 minimal fallback (ws too small) =======================

__global__ void k_init_o(unsigned int* __restrict__ mm) {
    int t = threadIdx.x;
    if (t < NB) { mm[2 * t] = 0xFFFFFFFFu; mm[2 * t + 1] = 0u; }
}

__global__ __launch_bounds__(256) void k_minmax_o(const float* __restrict__ xyz,
                                                  unsigned int* __restrict__ mm) {
    const int b = blockIdx.y;
    const float4* p4 = (const float4*)(xyz + (size_t)b * NPTS * 3);
    const int nthreads = gridDim.x * blockDim.x;
    const int t = blockIdx.x * blockDim.x + threadIdx.x;
    float lmin = INFINITY, lmax = -INFINITY;
    for (int g = t; g < NPTS / 4; g += nthreads) {
        float4 v0 = p4[3 * g + 0];
        float4 v1 = p4[3 * g + 1];
        float4 v2 = p4[3 * g + 2];
        lmin = fminf(fminf(fminf(lmin, v0.z), v1.y), fminf(v2.x, v2.w));
        lmax = fmaxf(fmaxf(fmaxf(lmax, v0.z), v1.y), fmaxf(v2.x, v2.w));
    }
    #pragma unroll
    for (int o = 32; o >= 1; o >>= 1) {
        lmin = fminf(lmin, __shfl_down(lmin, o));
        lmax = fmaxf(lmax, __shfl_down(lmax, o));
    }
    __shared__ float smin[4], smax[4];
    int wave = threadIdx.x >> 6, lane = threadIdx.x & 63;
    if (lane == 0) { smin[wave] = lmin; smax[wave] = lmax; }
    __syncthreads();
    if (threadIdx.x == 0) {
        float m = smin[0], M = smax[0];
        #pragma unroll
        for (int w = 1; w < 4; ++w) { m = fminf(m, smin[w]); M = fmaxf(M, smax[w]); }
        atomicMin(&mm[2 * b], f2o(m));
        atomicMax(&mm[2 * b + 1], f2o(M));
    }
}

__device__ __forceinline__ void hist_point_o(float x, float y, float z, int b,
                                             float zmin, float e1, float e2, float e3,
                                             float e4, float e5, float e6,
                                             float* __restrict__ out) {
    float gx = __fmul_rn(__fdiv_rn(__fadd_rn(x, 1.0f), 2.000001f), 255.0f);
    float gy = __fmul_rn(__fdiv_rn(__fadd_rn(y, 1.0f), 2.000001f), 255.0f);
    bool valid = (gy >= 0.0f) && (gy < 256.0f) && (gx >= 0.0f) && (gx < 256.0f);
    if (valid && z >= zmin && z < e6) {
        int s = (int)(z >= e1) + (int)(z >= e2) + (int)(z >= e3) +
                (int)(z >= e4) + (int)(z >= e5);
        atomicAdd(out + ((size_t)(b * NS + s) * IMG + ((int)gy) * WW + (int)gx), 1.0f);
    }
}

__global__ __launch_bounds__(256) void k_hist_o(const float* __restrict__ xyz,
                                                const unsigned int* __restrict__ mm,
                                                float* __restrict__ out) {
    const int b = blockIdx.y;
    const int t = blockIdx.x * blockDim.x + threadIdx.x;
    const float zmin = o2f(mm[2 * b]);
    const float zmax = o2f(mm[2 * b + 1]);
    float e1, e2, e3, e4, e5, e6;
    compute_edges(zmin, zmax, e1, e2, e3, e4, e5, e6);
    const float4* p4 = (const float4*)(xyz + (size_t)b * NPTS * 3);
    float4 v0 = p4[3 * t + 0];
    float4 v1 = p4[3 * t + 1];
    float4 v2 = p4[3 * t + 2];
    hist_point_o(v0.x, v0.y, v0.z, b, zmin, e1, e2, e3, e4, e5, e6, out);
    hist_point_o(v0.w, v1.x, v1.y, b, zmin, e1, e2, e3, e4, e5, e6, out);
    hist_point_o(v1.z, v1.w, v2.x, b, zmin, e1, e2, e3, e4, e5, e6, out);
    hist_point_o(v2.y, v2.z, v2.w, b, zmin, e1, e2, e3, e4, e5, e6, out);
}

__global__ __launch_bounds__(1024) void k_norm_o(float* __restrict__ out) {
    float4* img4 = (float4*)(out + (size_t)blockIdx.x * IMG);
    const int t = threadIdx.x;
    float lmin = INFINITY, lmax = -INFINITY;
    for (int i = t; i < IMG / 4; i += 1024) {
        float4 v = img4[i];
        lmin = fminf(lmin, fminf(fminf(v.x, v.y), fminf(v.z, v.w)));
        lmax = fmaxf(lmax, fmaxf(fmaxf(v.x, v.y), fmaxf(v.z, v.w)));
    }
    #pragma unroll
    for (int o = 32; o >= 1; o >>= 1) {
        lmin = fminf(lmin, __shfl_down(lmin, o));
        lmax = fmaxf(lmax, __shfl_down(lmax, o));
    }
    __shared__ float smin[16], smax[16], bc[2];
    int wave = t >> 6, lane = t & 63;
    if (lane == 0) { smin[wave] = lmin; smax[wave] = lmax; }
    __syncthreads();
    if (t == 0) {
        float m = smin[0], M = smax[0];
        #pragma unroll
        for (int w = 1; w < 16; ++w) { m = fminf(m, smin[w]); M = fmaxf(M, smax[w]); }
        bc[0] = m; bc[1] = M;
    }
    __syncthreads();
    const float mn = log1pf(bc[0]);
    const float mx = log1pf(bc[1]);
    const float denom = __fadd_rn(__fsub_rn(mx, mn), 1e-6f);
    for (int i = t; i < IMG / 4; i += 1024) {
        float4 v = img4[i];
        v.x = __fdiv_rn(__fsub_rn(log1pf(v.x), mn), denom);
        v.y = __fdiv_rn(__fsub_rn(log1pf(v.y), mn), denom);
        v.z = __fdiv_rn(__fsub_rn(log1pf(v.z), mn), denom);
        v.w = __fdiv_rn(__fsub_rn(log1pf(v.w), mn), denom);
        img4[i] = v;
    }
}

extern "C" void kernel_launch(void* const* d_in, const int* in_sizes, int n_in,
                              void* d_out, int out_size, void* d_ws, size_t ws_size,
                              hipStream_t stream) {
    const float* xyz = (const float*)d_in[0];
    float* out = (float*)d_out;
    unsigned int* ws = (unsigned int*)d_ws;

    if (ws_size >= WS_NEEDED) {
        char* bkt = (char*)d_ws + WS_BKT;
        hipLaunchKernelGGL(k_p1, dim3(NCH2, NB), dim3(1024), 0, stream, xyz, ws, bkt);
        hipLaunchKernelGGL(k_p2, dim3(RB, NB), dim3(1024), 0, stream, bkt, ws);
        hipLaunchKernelGGL(k_norm, dim3(NB * NS * 4), dim3(1024), 0, stream, bkt, ws, out);
    } else {
        hipMemsetAsync(d_out, 0, (size_t)out_size * sizeof(float), stream);
        hipLaunchKernelGGL(k_init_o, dim3(1), dim3(64), 0, stream, ws);
        hipLaunchKernelGGL(k_minmax_o, dim3(32, NB), dim3(256), 0, stream, xyz, ws);
        hipLaunchKernelGGL(k_hist_o, dim3(NPTS / 1024, NB), dim3(256), 0, stream, xyz, ws, out);
        hipLaunchKernelGGL(k_norm_o, dim3(NB * NS), dim3(1024), 0, stream, out);
    }
}

// Round 4
// 122.167 us; speedup vs baseline: 1.1670x; 1.0354x over previous
//
#include <hip/hip_runtime.h>
#include <math.h>

#define NB    32
#define NPTS  131072
#define NS    6
#define HH    256
#define WW    256
#define IMG   (HH * WW)          // 65536
#define RB    16                 // y-band regions per batch (16 rows each)
#define NCH2  64                 // sub-buckets per band = chunks per batch (R4: was 32)
#define SCAP2 160                // records per (chunk,band) sub-bucket (mean ~70, +11 sigma)
#define KEYB  (NCH2 * SCAP2 * 2) // 20480 B of u16 keys per region
#define ZB    (NCH2 * SCAP2 * 4) // 40960 B of f32 z per region
#define REG3  (KEYB + ZB)        // 61440 B per (b,band) region (256-aligned)
// phase2 reuses first 24576 B of each region as u8 hist [s][row16][col]

// ---- ws layout (bytes) ----
// cnts @ 0      : NB*RB*NCH2 u32 = 131072  (per (b,band,chunk) record counts)
// pmm  @ 131072 : NB*NCH2 float2 = 16384   (per-chunk z min/max partials)
// pmin @ 147456 : NB*RB*NS u32   = 12288   (per (b,band,s) count min)
// pmax @ 159744 : NB*RB*NS u32   = 12288
// bkt  @ 172032 : NB*RB regions x 61440 B  = 31,457,280
#define WS_CNT     0
#define WS_PMM     (131072 / 8)         // float2 index
#define WS_PMIN    (147456 / 4)
#define WS_PMAX    (159744 / 4)
#define WS_BKT     172032
#define WS_NEEDED  ((size_t)WS_BKT + (size_t)NB * RB * REG3)   // 31,629,312

// ---- monotone float<->uint encoding (fallback path only) ----
__device__ __forceinline__ unsigned int f2o(float f) {
    unsigned int u = __float_as_uint(f);
    return (u & 0x80000000u) ? ~u : (u | 0x80000000u);
}
__device__ __forceinline__ float o2f(unsigned int u) {
    return __uint_as_float((u & 0x80000000u) ? (u ^ 0x80000000u) : ~u);
}

// np.linspace(0,1,7).astype(f32) interior values as exact hexfloats
#define A16 0x1.555556p-3f
#define A26 0x1.555556p-2f
#define A36 0.5f
#define A46 0x1.555556p-1f
#define A56 0x1.AAAAAAp-1f
// loose prefilter: approx scale 255/2.000001 (error vs exact path < 6e-5)
#define C1A 127.49994f

__device__ __forceinline__ void compute_edges(float zmin, float zmax,
                                              float& e1, float& e2, float& e3,
                                              float& e4, float& e5, float& e6) {
    float range = __fsub_rn(zmax, zmin);
    e1 = __fadd_rn(zmin, __fmul_rn(range, A16));
    e2 = __fadd_rn(zmin, __fmul_rn(range, A26));
    e3 = __fadd_rn(zmin, __fmul_rn(range, A36));
    e4 = __fadd_rn(zmin, __fmul_rn(range, A46));
    e5 = __fadd_rn(zmin, __fmul_rn(range, A56));
    e6 = __fadd_rn(zmin, range);
}

// ======================= fast path (3 kernels, no global atomics) =======================

// k_p1: read xyz once; stage valid records per band in LDS (u16 key + f32 z split);
// flush coalesced into statically-owned sub-bucket slots; plain-store counts + z minmax.
// R4: 512-thread blocks, 64 chunks/batch -> 4 blocks/CU (was 2): halves barrier scope,
// doubles independent blocks per CU to hide the atomic-return/store latency chains.
// Same per-point math, same record semantics => bit-identical output.
__global__ __launch_bounds__(512) void k_p1(const float* __restrict__ xyz,
                                            unsigned int* __restrict__ ws,
                                            char* __restrict__ bkt) {
    const int b  = blockIdx.y;
    const int cx = blockIdx.x;                 // 0..63 chunk within batch
    const int t  = threadIdx.x;                // 512 threads, 4 points each
    const int wave = t >> 6;
    __shared__ unsigned int cnt[RB];
    __shared__ unsigned short stage_k[RB][SCAP2];   // 5120 B
    __shared__ float stage_z[RB][SCAP2];            // 10240 B
    __shared__ float smin[8], smax[8];
    if (t < RB) cnt[t] = 0u;
    __syncthreads();

    const int g = cx * 512 + t;                // 0..32767 = NPTS/4
    const float4* p4 = (const float4*)(xyz + (size_t)b * NPTS * 3);
    float4 v0 = p4[3 * g + 0];
    float4 v1 = p4[3 * g + 1];
    float4 v2 = p4[3 * g + 2];
    float xs[4] = {v0.x, v0.w, v1.z, v2.y};
    float ys[4] = {v0.y, v1.x, v1.w, v2.z};
    float zs[4] = {v0.z, v1.y, v2.x, v2.w};

    #pragma unroll
    for (int p = 0; p < 4; ++p) {
        float ty = __fadd_rn(ys[p], 1.0f);
        float tx = __fadd_rn(xs[p], 1.0f);
        // loose prefilter (over-accepting); exact path only for plausible pts
        float gya = ty * C1A, gxa = tx * C1A;
        if (gya > -0.02f && gya < 256.02f && gxa > -0.02f && gxa < 256.02f) {
            // bit-exact reference coord math (all f32-rounded steps, no FMA)
            float gy = __fmul_rn(__fdiv_rn(ty, 2.000001f), 255.0f);
            float gx = __fmul_rn(__fdiv_rn(tx, 2.000001f), 255.0f);
            if (gy >= 0.0f && gy < 256.0f && gx >= 0.0f && gx < 256.0f) {
                int iy = (int)gy, ix = (int)gx;
                int r = iy >> 4;
                unsigned int off = atomicAdd(&cnt[r], 1u);
                if (off < SCAP2) {
                    stage_k[r][off] = (unsigned short)((iy << 8) | ix);
                    stage_z[r][off] = zs[p];
                }
            }
        }
    }

    // fused z min/max over ALL points (reference reduces over all N)
    float lmin = fminf(fminf(zs[0], zs[1]), fminf(zs[2], zs[3]));
    float lmax = fmaxf(fmaxf(zs[0], zs[1]), fmaxf(zs[2], zs[3]));
    #pragma unroll
    for (int o = 32; o >= 1; o >>= 1) {
        lmin = fminf(lmin, __shfl_down(lmin, o));
        lmax = fmaxf(lmax, __shfl_down(lmax, o));
    }
    if ((t & 63) == 0) { smin[wave] = lmin; smax[wave] = lmax; }
    __syncthreads();   // cnt + stage + smin/smax final

    if (t == 0) {
        float m = smin[0], M = smax[0];
        #pragma unroll
        for (int w = 1; w < 8; ++w) { m = fminf(m, smin[w]); M = fmaxf(M, smax[w]); }
        ((float2*)ws)[WS_PMM + b * NCH2 + cx] = make_float2(m, M);   // plain store
    }
    if (t < RB)
        ws[WS_CNT + (b * RB + t) * NCH2 + cx] = min(cnt[t], (unsigned)SCAP2);

    // coalesced flush: this block statically owns slot range [cx*SCAP2, +SCAP2)
    for (int r = 0; r < RB; ++r) {
        unsigned int n = min(cnt[r], (unsigned)SCAP2);
        char* region = bkt + (size_t)(b * RB + r) * REG3;
        // keys flushed as paired u32 (one trailing garbage u16 beyond n is never read)
        unsigned int* kdst = (unsigned int*)(region + (size_t)cx * SCAP2 * 2);
        const unsigned int* ksrc = (const unsigned int*)&stage_k[r][0];
        unsigned int nk = (n + 1) >> 1;
        for (unsigned int i = t; i < nk; i += 512) kdst[i] = ksrc[i];
        float* zdst = (float*)(region + KEYB) + (size_t)cx * SCAP2;
        for (unsigned int i = t; i < n; i += 512) zdst[i] = stage_z[r][i];
    }
}

// k_p2: per (b,band) LDS u16 histogram from records; static sub-bucket ownership
// (16 lanes per bucket, no prefix-sum, no binary search). 1024 threads.
__global__ __launch_bounds__(1024) void k_p2(char* __restrict__ bkt,
                                             unsigned int* __restrict__ ws) {
    const int r = blockIdx.x;        // 0..15 (y band)
    const int b = blockIdx.y;
    const int t = threadIdx.x;       // 1024 threads
    const int wave = t >> 6;
    __shared__ unsigned int hist[NS * 16 * WW / 2];  // 12288 u32 = 24576 u16 counts
    __shared__ unsigned int cct[NCH2];
    __shared__ unsigned int rmin[16][NS], rmax[16][NS];

    // reduce per-chunk z partials (uniform scalar loads)
    const float2* pmm = (const float2*)ws + WS_PMM + b * NCH2;
    float zmin = INFINITY, zmax = -INFINITY;
    for (int i = 0; i < NCH2; ++i) {
        float2 v = pmm[i];
        zmin = fminf(zmin, v.x); zmax = fmaxf(zmax, v.y);
    }
    float e1, e2, e3, e4, e5, e6;
    compute_edges(zmin, zmax, e1, e2, e3, e4, e5, e6);

    for (int i = t; i < NS * 16 * WW / 2; i += 1024) hist[i] = 0u;
    if (t < NCH2) cct[t] = ws[WS_CNT + (b * RB + r) * NCH2 + t];
    __syncthreads();

    char* region = bkt + (size_t)(b * RB + r) * REG3;
    const unsigned short* keys = (const unsigned short*)region;
    const float* zarr = (const float*)(region + KEYB);

    // static ownership: 16 lanes per bucket (64 buckets)
    const int c = t >> 4;                    // bucket 0..63
    const int l = t & 15;
    const unsigned int n = cct[c];           // <= SCAP2 (capped by k_p1)
    const unsigned int base = (unsigned int)c * SCAP2;
    for (unsigned int i = l; i < n; i += 16) {
        unsigned int j = base + i;
        unsigned int key = keys[j];
        float z = zarr[j];
        if (z >= zmin && z < e6) {
            int s = (int)(z >= e1) + (int)(z >= e2) + (int)(z >= e3) +
                    (int)(z >= e4) + (int)(z >= e5);
            int bin = (s << 12) | ((int)key & 0x0F00) | ((int)key & 0xFF);
            atomicAdd(&hist[bin >> 1], 1u << ((bin & 1) * 16));
        }
    }
    __syncthreads();   // all record reads done -> safe to overwrite region

    // write u8-packed hist into OWN region (counts < 256: Poisson lambda ~0.6, max ~10)
    unsigned int* dst = (unsigned int*)region;   // 6144 u32 = 24576 B, [s][row16][col] u8
    #pragma unroll
    for (int s = 0; s < NS; ++s) {
        int i = (s << 10) + t;                   // u32-of-u8 index: 1024 per slice
        unsigned int u = hist[2 * i], v = hist[2 * i + 1];
        unsigned int c0 = u & 0xFFFFu, c1 = u >> 16;
        unsigned int c2 = v & 0xFFFFu, c3 = v >> 16;
        unsigned int a = min(min(c0, c1), min(c2, c3));
        unsigned int m = max(max(c0, c1), max(c2, c3));
        dst[i] = (u & 0xFFu) | ((u >> 8) & 0xFF00u) |
                 ((v & 0xFFu) << 16) | (((v >> 8) & 0xFF00u) << 16);
        #pragma unroll
        for (int o = 32; o >= 1; o >>= 1) {
            a = min(a, (unsigned)__shfl_down((int)a, o));
            m = max(m, (unsigned)__shfl_down((int)m, o));
        }
        if ((t & 63) == 0) { rmin[wave][s] = a; rmax[wave][s] = m; }
    }
    __syncthreads();
    if (t < NS) {
        unsigned int a = rmin[0][t], m = rmax[0][t];
        #pragma unroll
        for (int w = 1; w < 16; ++w) { a = min(a, rmin[w][t]); m = max(m, rmax[w][t]); }
        ws[WS_PMIN + (b * RB + r) * NS + t] = a;   // plain stores
        ws[WS_PMAX + (b * RB + r) * NS + t] = m;
    }
}

// k_norm: complete LUT normalize (u8 counts => 256-entry LUT covers every value);
// per element = u32 load (4 cells), 4 LDS lookups, float4 store. Pure streaming.
__global__ __launch_bounds__(1024) void k_norm(const char* __restrict__ bkt,
                                               const unsigned int* __restrict__ ws,
                                               float* __restrict__ out) {
    const int q = blockIdx.x;          // 768 blocks: (b*6+s)*4 + quarter
    const int img = q >> 2;            // b*NS+s
    const int quarter = q & 3;
    const int b = img / NS, s = img - b * NS;
    const int t = threadIdx.x;
    __shared__ float bc[2];
    __shared__ float lut[256];

    if (t < 64) {   // reduce 16 band partials for (b,s)
        unsigned int a = 0xFFFFFFFFu, m = 0u;
        if (t < RB) {
            a = ws[WS_PMIN + (b * RB + t) * NS + s];
            m = ws[WS_PMAX + (b * RB + t) * NS + s];
        }
        #pragma unroll
        for (int o = 8; o >= 1; o >>= 1) {
            a = min(a, (unsigned)__shfl_down((int)a, o));
            m = max(m, (unsigned)__shfl_down((int)m, o));
        }
        if (t == 0) { bc[0] = log1pf((float)a); bc[1] = log1pf((float)m); }
    }
    __syncthreads();
    const float mn = bc[0];
    const float denom = __fadd_rn(__fsub_rn(bc[1], mn), 1e-6f);
    if (t < 256)
        lut[t] = __fdiv_rn(__fsub_rn(log1pf((float)t), mn), denom);
    __syncthreads();

    float4* out4 = (float4*)out + (size_t)img * (IMG / 4) + quarter * 4096;
    #pragma unroll
    for (int j = 0; j < 4; ++j) {
        int idx4 = j * 1024 + t;                  // 4096 float4 per quarter
        int f = idx4 << 2;
        int y = (quarter << 6) + (f >> 8);
        int x = f & 255;
        const char* region = bkt + (size_t)(b * RB + (y >> 4)) * REG3;
        unsigned int u = *(const unsigned int*)(region + ((((s << 4) | (y & 15)) << 8) | x));
        float4 v;
        v.x = lut[u & 0xFFu];
        v.y = lut[(u >> 8) & 0xFFu];
        v.z = lut[(u >> 16) & 0xFFu];
        v.w = lut[u >> 24];
        out4[idx4] = v;
    }
}

// ======================= R1 minimal fallback (ws too small) =======================

__global__ void k_init_o(unsigned int* __restrict__ mm) {
    int t = threadIdx.x;
    if (t < NB) { mm[2 * t] = 0xFFFFFFFFu; mm[2 * t + 1] = 0u; }
}

__global__ __launch_bounds__(256) void k_minmax_o(const float* __restrict__ xyz,
                                                  unsigned int* __restrict__ mm) {
    const int b = blockIdx.y;
    const float4* p4 = (const float4*)(xyz + (size_t)b * NPTS * 3);
    const int nthreads = gridDim.x * blockDim.x;
    const int t = blockIdx.x * blockDim.x + threadIdx.x;
    float lmin = INFINITY, lmax = -INFINITY;
    for (int g = t; g < NPTS / 4; g += nthreads) {
        float4 v0 = p4[3 * g + 0];
        float4 v1 = p4[3 * g + 1];
        float4 v2 = p4[3 * g + 2];
        lmin = fminf(fminf(fminf(lmin, v0.z), v1.y), fminf(v2.x, v2.w));
        lmax = fmaxf(fmaxf(fmaxf(lmax, v0.z), v1.y), fmaxf(v2.x, v2.w));
    }
    #pragma unroll
    for (int o = 32; o >= 1; o >>= 1) {
        lmin = fminf(lmin, __shfl_down(lmin, o));
        lmax = fmaxf(lmax, __shfl_down(lmax, o));
    }
    __shared__ float smin[4], smax[4];
    int wave = threadIdx.x >> 6, lane = threadIdx.x & 63;
    if (lane == 0) { smin[wave] = lmin; smax[wave] = lmax; }
    __syncthreads();
    if (threadIdx.x == 0) {
        float m = smin[0], M = smax[0];
        #pragma unroll
        for (int w = 1; w < 4; ++w) { m = fminf(m, smin[w]); M = fmaxf(M, smax[w]); }
        atomicMin(&mm[2 * b], f2o(m));
        atomicMax(&mm[2 * b + 1], f2o(M));
    }
}

__device__ __forceinline__ void hist_point_o(float x, float y, float z, int b,
                                             float zmin, float e1, float e2, float e3,
                                             float e4, float e5, float e6,
                                             float* __restrict__ out) {
    float gx = __fmul_rn(__fdiv_rn(__fadd_rn(x, 1.0f), 2.000001f), 255.0f);
    float gy = __fmul_rn(__fdiv_rn(__fadd_rn(y, 1.0f), 2.000001f), 255.0f);
    bool valid = (gy >= 0.0f) && (gy < 256.0f) && (gx >= 0.0f) && (gx < 256.0f);
    if (valid && z >= zmin && z < e6) {
        int s = (int)(z >= e1) + (int)(z >= e2) + (int)(z >= e3) +
                (int)(z >= e4) + (int)(z >= e5);
        atomicAdd(out + ((size_t)(b * NS + s) * IMG + ((int)gy) * WW + (int)gx), 1.0f);
    }
}

__global__ __launch_bounds__(256) void k_hist_o(const float* __restrict__ xyz,
                                                const unsigned int* __restrict__ mm,
                                                float* __restrict__ out) {
    const int b = blockIdx.y;
    const int t = blockIdx.x * blockDim.x + threadIdx.x;
    const float zmin = o2f(mm[2 * b]);
    const float zmax = o2f(mm[2 * b + 1]);
    float e1, e2, e3, e4, e5, e6;
    compute_edges(zmin, zmax, e1, e2, e3, e4, e5, e6);
    const float4* p4 = (const float4*)(xyz + (size_t)b * NPTS * 3);
    float4 v0 = p4[3 * t + 0];
    float4 v1 = p4[3 * t + 1];
    float4 v2 = p4[3 * t + 2];
    hist_point_o(v0.x, v0.y, v0.z, b, zmin, e1, e2, e3, e4, e5, e6, out);
    hist_point_o(v0.w, v1.x, v1.y, b, zmin, e1, e2, e3, e4, e5, e6, out);
    hist_point_o(v1.z, v1.w, v2.x, b, zmin, e1, e2, e3, e4, e5, e6, out);
    hist_point_o(v2.y, v2.z, v2.w, b, zmin, e1, e2, e3, e4, e5, e6, out);
}

__global__ __launch_bounds__(1024) void k_norm_o(float* __restrict__ out) {
    float4* img4 = (float4*)(out + (size_t)blockIdx.x * IMG);
    const int t = threadIdx.x;
    float lmin = INFINITY, lmax = -INFINITY;
    for (int i = t; i < IMG / 4; i += 1024) {
        float4 v = img4[i];
        lmin = fminf(lmin, fminf(fminf(v.x, v.y), fminf(v.z, v.w)));
        lmax = fmaxf(lmax, fmaxf(fmaxf(v.x, v.y), fmaxf(v.z, v.w)));
    }
    #pragma unroll
    for (int o = 32; o >= 1; o >>= 1) {
        lmin = fminf(lmin, __shfl_down(lmin, o));
        lmax = fmaxf(lmax, __shfl_down(lmax, o));
    }
    __shared__ float smin[16], smax[16], bc[2];
    int wave = t >> 6, lane = t & 63;
    if (lane == 0) { smin[wave] = lmin; smax[wave] = lmax; }
    __syncthreads();
    if (t == 0) {
        float m = smin[0], M = smax[0];
        #pragma unroll
        for (int w = 1; w < 16; ++w) { m = fminf(m, smin[w]); M = fmaxf(M, smax[w]); }
        bc[0] = m; bc[1] = M;
    }
    __syncthreads();
    const float mn = log1pf(bc[0]);
    const float mx = log1pf(bc[1]);
    const float denom = __fadd_rn(__fsub_rn(mx, mn), 1e-6f);
    for (int i = t; i < IMG / 4; i += 1024) {
        float4 v = img4[i];
        v.x = __fdiv_rn(__fsub_rn(log1pf(v.x), mn), denom);
        v.y = __fdiv_rn(__fsub_rn(log1pf(v.y), mn), denom);
        v.z = __fdiv_rn(__fsub_rn(log1pf(v.z), mn), denom);
        v.w = __fdiv_rn(__fsub_rn(log1pf(v.w), mn), denom);
        img4[i] = v;
    }
}

extern "C" void kernel_launch(void* const* d_in, const int* in_sizes, int n_in,
                              void* d_out, int out_size, void* d_ws, size_t ws_size,
                              hipStream_t stream) {
    const float* xyz = (const float*)d_in[0];
    float* out = (float*)d_out;
    unsigned int* ws = (unsigned int*)d_ws;

    if (ws_size >= WS_NEEDED) {
        char* bkt = (char*)d_ws + WS_BKT;
        hipLaunchKernelGGL(k_p1, dim3(NCH2, NB), dim3(512), 0, stream, xyz, ws, bkt);
        hipLaunchKernelGGL(k_p2, dim3(RB, NB), dim3(1024), 0, stream, bkt, ws);
        hipLaunchKernelGGL(k_norm, dim3(NB * NS * 4), dim3(1024), 0, stream, bkt, ws, out);
    } else {
        hipMemsetAsync(d_out, 0, (size_t)out_size * sizeof(float), stream);
        hipLaunchKernelGGL(k_init_o, dim3(1), dim3(64), 0, stream, ws);
        hipLaunchKernelGGL(k_minmax_o, dim3(32, NB), dim3(256), 0, stream, xyz, ws);
        hipLaunchKernelGGL(k_hist_o, dim3(NPTS / 1024, NB), dim3(256), 0, stream, xyz, ws, out);
        hipLaunchKernelGGL(k_norm_o, dim3(NB * NS), dim3(1024), 0, stream, out);
    }
}